// Round 13
// baseline (693.369 us; speedup 1.0000x reference)
//
#include <hip/hip_runtime.h>
#include <math.h>

#define N_NODES 50000
#define E_EDGES 1600000
#define F_IN_DIM 256
#define H_HEADS 4
#define C_CH 32
#define HC 128
#define NUM_CLASSES 16
#define NUM_GRAPHS 64
#define ETOT (E_EDGES + N_NODES)
#define NEG_SLOPE 0.2f
#define SCAN_BLOCKS ((N_NODES + 255) / 256)   // 196
#define NBUCK ((N_NODES + 255) / 256)         // 196 coarse buckets (256 nodes each)
#define SCAT_BLOCKS 512
#define POOL_SPLIT 8

// float -> bf16 (round-to-nearest-even)
__device__ __forceinline__ unsigned short f2bf(float f) {
    unsigned u = __float_as_uint(f);
    return (unsigned short)((u + 0x7FFFu + ((u >> 16) & 1u)) >> 16);
}

// ---- register-blocked GEMM + fused alpha + bf16 output ----
// H16[n,0:128] = bf16(X[n,0:K] @ W[K,128]); as/ad[n,h] = sum_c h*att (fp32, from regs)
template <int K>
__global__ __launch_bounds__(256) void gemm_rb(const float* __restrict__ X,
                                               const float* __restrict__ W,
                                               const float* __restrict__ att_src,
                                               const float* __restrict__ att_dst,
                                               unsigned short* __restrict__ H16,
                                               float* __restrict__ as,
                                               float* __restrict__ ad) {
    __shared__ float xs[32][68];
    const int n0 = blockIdx.x * 64;
    const int tid = threadIdx.x;
    const int rg = tid >> 5;
    const int cg = tid & 31;
    const int r0 = rg * 8;
    const int c0 = cg * 4;
    float acc[8][4];
#pragma unroll
    for (int i = 0; i < 8; ++i)
#pragma unroll
        for (int j = 0; j < 4; ++j) acc[i][j] = 0.f;

    for (int k0 = 0; k0 < K; k0 += 32) {
        __syncthreads();
#pragma unroll
        for (int L = tid; L < 512; L += 256) {
            int row = L >> 3;
            int kq = L & 7;
            int n = n0 + row;
            float4 v = make_float4(0.f, 0.f, 0.f, 0.f);
            if (n < N_NODES)
                v = *reinterpret_cast<const float4*>(&X[(size_t)n * K + k0 + kq * 4]);
            xs[kq * 4 + 0][row] = v.x;
            xs[kq * 4 + 1][row] = v.y;
            xs[kq * 4 + 2][row] = v.z;
            xs[kq * 4 + 3][row] = v.w;
        }
        __syncthreads();
#pragma unroll 8
        for (int k = 0; k < 32; ++k) {
            const float4 w = *reinterpret_cast<const float4*>(&W[(size_t)(k0 + k) * HC + c0]);
            const float4 xa = *reinterpret_cast<const float4*>(&xs[k][r0]);
            const float4 xb = *reinterpret_cast<const float4*>(&xs[k][r0 + 4]);
            acc[0][0] = fmaf(xa.x, w.x, acc[0][0]);
            acc[0][1] = fmaf(xa.x, w.y, acc[0][1]);
            acc[0][2] = fmaf(xa.x, w.z, acc[0][2]);
            acc[0][3] = fmaf(xa.x, w.w, acc[0][3]);
            acc[1][0] = fmaf(xa.y, w.x, acc[1][0]);
            acc[1][1] = fmaf(xa.y, w.y, acc[1][1]);
            acc[1][2] = fmaf(xa.y, w.z, acc[1][2]);
            acc[1][3] = fmaf(xa.y, w.w, acc[1][3]);
            acc[2][0] = fmaf(xa.z, w.x, acc[2][0]);
            acc[2][1] = fmaf(xa.z, w.y, acc[2][1]);
            acc[2][2] = fmaf(xa.z, w.z, acc[2][2]);
            acc[2][3] = fmaf(xa.z, w.w, acc[2][3]);
            acc[3][0] = fmaf(xa.w, w.x, acc[3][0]);
            acc[3][1] = fmaf(xa.w, w.y, acc[3][1]);
            acc[3][2] = fmaf(xa.w, w.z, acc[3][2]);
            acc[3][3] = fmaf(xa.w, w.w, acc[3][3]);
            acc[4][0] = fmaf(xb.x, w.x, acc[4][0]);
            acc[4][1] = fmaf(xb.x, w.y, acc[4][1]);
            acc[4][2] = fmaf(xb.x, w.z, acc[4][2]);
            acc[4][3] = fmaf(xb.x, w.w, acc[4][3]);
            acc[5][0] = fmaf(xb.y, w.x, acc[5][0]);
            acc[5][1] = fmaf(xb.y, w.y, acc[5][1]);
            acc[5][2] = fmaf(xb.y, w.z, acc[5][2]);
            acc[5][3] = fmaf(xb.y, w.w, acc[5][3]);
            acc[6][0] = fmaf(xb.z, w.x, acc[6][0]);
            acc[6][1] = fmaf(xb.z, w.y, acc[6][1]);
            acc[6][2] = fmaf(xb.z, w.z, acc[6][2]);
            acc[6][3] = fmaf(xb.z, w.w, acc[6][3]);
            acc[7][0] = fmaf(xb.w, w.x, acc[7][0]);
            acc[7][1] = fmaf(xb.w, w.y, acc[7][1]);
            acc[7][2] = fmaf(xb.w, w.z, acc[7][2]);
            acc[7][3] = fmaf(xb.w, w.w, acc[7][3]);
        }
    }
    // epilogue: bf16 store + fused alpha (head h = cg>>3, channels c0..c0+3)
    const int h = cg >> 3;
    const int cb = c0 & 31;
    const float4 av = *reinterpret_cast<const float4*>(&att_src[h * C_CH + cb]);
    const float4 dv = *reinterpret_cast<const float4*>(&att_dst[h * C_CH + cb]);
#pragma unroll
    for (int i = 0; i < 8; ++i) {
        int n = n0 + r0 + i;
        float sa = acc[i][0] * av.x + acc[i][1] * av.y + acc[i][2] * av.z + acc[i][3] * av.w;
        float sd = acc[i][0] * dv.x + acc[i][1] * dv.y + acc[i][2] * dv.z + acc[i][3] * dv.w;
#pragma unroll
        for (int off = 1; off < 8; off <<= 1) {
            sa += __shfl_xor(sa, off, 64);
            sd += __shfl_xor(sd, off, 64);
        }
        if (n < N_NODES) {
            ushort4 b;
            b.x = f2bf(acc[i][0]);
            b.y = f2bf(acc[i][1]);
            b.z = f2bf(acc[i][2]);
            b.w = f2bf(acc[i][3]);
            *reinterpret_cast<ushort4*>(&H16[(size_t)n * HC + c0]) = b;
            if ((cg & 7) == 0) {
                as[n * 4 + h] = sa;
                ad[n * 4 + h] = sd;
            }
        }
    }
}

// ================= CSR build (once per call) =================
__global__ void count_deg_kernel(const int* __restrict__ ei, int* __restrict__ deg) {
    int e = blockIdx.x * blockDim.x + threadIdx.x;
    if (e >= ETOT) return;
    int d = (e < E_EDGES) ? ei[E_EDGES + e] : (e - E_EDGES);
    atomicAdd(&deg[d], 1);
}

__global__ __launch_bounds__(256) void scan_block_kernel(const int* __restrict__ deg,
                                                         int* __restrict__ excl,
                                                         int* __restrict__ bsum) {
    __shared__ int tmp[256];
    int i = blockIdx.x * 256 + threadIdx.x;
    int v = (i < N_NODES) ? deg[i] : 0;
    tmp[threadIdx.x] = v;
    __syncthreads();
    for (int off = 1; off < 256; off <<= 1) {
        int t = (threadIdx.x >= off) ? tmp[threadIdx.x - off] : 0;
        __syncthreads();
        tmp[threadIdx.x] += t;
        __syncthreads();
    }
    if (i < N_NODES) excl[i] = tmp[threadIdx.x] - v;
    if (threadIdx.x == 255) bsum[blockIdx.x] = tmp[255];
}

__global__ __launch_bounds__(256) void scan_tops_kernel(int* __restrict__ bsum) {
    __shared__ int tmp[256];
    int t = threadIdx.x;
    int v = (t < SCAN_BLOCKS) ? bsum[t] : 0;
    tmp[t] = v;
    __syncthreads();
    for (int off = 1; off < 256; off <<= 1) {
        int u = (t >= off) ? tmp[t - off] : 0;
        __syncthreads();
        tmp[t] += u;
        __syncthreads();
    }
    if (t < SCAN_BLOCKS) bsum[t] = tmp[t] - v;
}

// finalize row_start; seed per-bucket cursors for the coarse scatter
__global__ void scan_add_kernel(int* __restrict__ excl, const int* __restrict__ bsum,
                                int* __restrict__ bcursor) {
    int i = blockIdx.x * blockDim.x + threadIdx.x;
    if (i >= N_NODES) return;
    int s = excl[i] + bsum[i >> 8];
    excl[i] = s;                              // row_start
    if ((i & 255) == 0) bcursor[i >> 8] = s;  // bucket base
}

// ---- coarse scatter: bin packed edges (d<<16|s) by d>>8 ----
__global__ __launch_bounds__(256) void bucket_scatter_kernel(const int* __restrict__ ei,
                                                             int* __restrict__ bcursor,
                                                             unsigned* __restrict__ bucket_buf) {
    __shared__ int hist[NBUCK];
    __shared__ int base[NBUCK];
    const int tid = threadIdx.x;
    const int chunk = (ETOT + SCAT_BLOCKS - 1) / SCAT_BLOCKS;
    const int e0 = blockIdx.x * chunk;
    const int e1 = min(e0 + chunk, ETOT);
    for (int i = tid; i < NBUCK; i += 256) hist[i] = 0;
    __syncthreads();
    for (int e = e0 + tid; e < e1; e += 256) {
        int d = (e < E_EDGES) ? ei[E_EDGES + e] : (e - E_EDGES);
        atomicAdd(&hist[d >> 8], 1);
    }
    __syncthreads();
    for (int i = tid; i < NBUCK; i += 256) {
        int cnt = hist[i];
        base[i] = (cnt > 0) ? atomicAdd(&bcursor[i], cnt) : 0;
        hist[i] = 0;  // reuse as local cursor
    }
    __syncthreads();
    for (int e = e0 + tid; e < e1; e += 256) {
        int s, d;
        if (e < E_EDGES) { s = ei[e]; d = ei[E_EDGES + e]; }
        else             { s = d = e - E_EDGES; }
        int b = d >> 8;
        int pos = base[b] + atomicAdd(&hist[b], 1);
        bucket_buf[pos] = ((unsigned)d << 16) | (unsigned)s;
    }
}

// ---- fine scatter: one block per bucket, LDS cursors, private window ----
__global__ __launch_bounds__(256) void bucket_sort_kernel(const unsigned* __restrict__ bucket_buf,
                                                          const int* __restrict__ row_start,
                                                          int* __restrict__ elist) {
    __shared__ int cur[256];
    const int b = blockIdx.x;
    const int n0 = b * 256;
    const int tid = threadIdx.x;
    if (n0 + tid < N_NODES) cur[tid] = row_start[n0 + tid];
    const int start = row_start[n0];
    const int end = (b == NBUCK - 1) ? ETOT : row_start[n0 + 256];
    __syncthreads();
    for (int j = start + tid; j < end; j += 256) {
        unsigned p = bucket_buf[j];
        int d = (int)(p >> 16);
        int s = (int)(p & 0xffffu);
        int pos = atomicAdd(&cur[d - n0], 1);
        elist[pos] = s;
    }
}

// ============ fused gather GAT: one wave per node, barrier-free ============
// 256 threads = 4 waves = 4 nodes. Lane l owns channels {2l, 2l+1}; head = l>>4.
// Softmax in 16-edge sub-chunks: lane l computes logit for (head l>>4, edge l&15);
// 4-step shfl reductions within 16-lane head groups. Gather: p and s broadcast via
// __shfl from lane (l&48)|j; one u32 load = ushort2 = full 256B row per wave.
__global__ __launch_bounds__(256) void gat_gather_kernel(const int* __restrict__ row_start,
                                                         const int* __restrict__ deg,
                                                         const int* __restrict__ elist,
                                                         const float* __restrict__ as,
                                                         const float* __restrict__ ad,
                                                         const unsigned short* __restrict__ H16,
                                                         const float* __restrict__ bias,
                                                         float* __restrict__ out) {
    const int n = blockIdx.x * 4 + (threadIdx.x >> 6);
    if (n >= N_NODES) return;
    const int lane = threadIdx.x & 63;
    const int hg = lane >> 4;       // head
    const int j16 = lane & 15;      // edge-in-subchunk
    const int row = row_start[n];
    const int len = deg[n];
    const float ad_n = ad[n * 4 + hg];

    float m = -INFINITY, z = 0.f, acc0 = 0.f, acc1 = 0.f;

    for (int base = 0; base < len; base += 16) {
        const int cl = min(16, len - base);
        // lane l holds edge (l&15) of this sub-chunk
        int sval = (j16 < cl) ? elist[row + base + j16] : 0;

        // logit for (head hg, edge j16)
        float ev = -INFINITY;
        if (j16 < cl) {
            ev = as[sval * 4 + hg] + ad_n;
            ev = ev > 0.f ? ev : ev * NEG_SLOPE;
        }
        // max over the 16-lane head group
        float cm = ev;
#pragma unroll
        for (int off = 8; off > 0; off >>= 1)
            cm = fmaxf(cm, __shfl_xor(cm, off, 64));
        float mnew = fmaxf(m, cm);
        float scale = __expf(m - mnew);   // first chunk: exp(-inf)=0
        z *= scale;
        acc0 *= scale;
        acc1 *= scale;
        m = mnew;
        float p = (j16 < cl) ? __expf(ev - m) : 0.f;
        float ps = p;
#pragma unroll
        for (int off = 8; off > 0; off >>= 1)
            ps += __shfl_xor(ps, off, 64);
        z += ps;

        // gather: lane (lane&48)|j holds s and p for (head hg, edge j)
        for (int j = 0; j < cl; ++j) {
            int src = (lane & 48) | j;
            int sj = __shfl(sval, src, 64);
            float pj = __shfl(p, src, 64);
            unsigned u = *reinterpret_cast<const unsigned*>(&H16[(size_t)sj * HC + 2 * lane]);
            float hv0 = __uint_as_float(u << 16);
            float hv1 = __uint_as_float(u & 0xffff0000u);
            acc0 = fmaf(pj, hv0, acc0);
            acc1 = fmaf(pj, hv1, acc1);
        }
    }
    float inv = 1.0f / z;
    float v0 = acc0 * inv + bias[2 * lane];
    float v1 = acc1 * inv + bias[2 * lane + 1];
    float2 r;
    r.x = v0 > 0.f ? v0 : 0.f;
    r.y = v1 > 0.f ? v1 : 0.f;
    *reinterpret_cast<float2*>(&out[(size_t)n * HC + 2 * lane]) = r;
}

// ---- graph boundaries via binary search on sorted batch ----
__global__ void boundary_kernel(const int* __restrict__ batch,
                                int* __restrict__ gstart,
                                float* __restrict__ cntf) {
    int g = threadIdx.x;
    if (g <= NUM_GRAPHS) {
        int lo = 0, hi = N_NODES;
        while (lo < hi) {
            int mid = (lo + hi) >> 1;
            if (batch[mid] < g) lo = mid + 1; else hi = mid;
        }
        gstart[g] = lo;
    }
    __syncthreads();
    if (g < NUM_GRAPHS) cntf[g] = (float)(gstart[g + 1] - gstart[g]);
}

// ---- pool: 8 blocks per graph, register accumulation, 1 atomic per thread ----
__global__ __launch_bounds__(128) void pool_seg_kernel(const float* __restrict__ out,
                                                       const int* __restrict__ gstart,
                                                       float* __restrict__ sums) {
    const int g = blockIdx.x >> 3;
    const int split = blockIdx.x & 7;
    const int c = threadIdx.x;
    const int start = gstart[g], end = gstart[g + 1];
    const int len = end - start;
    const int chunk = (len + POOL_SPLIT - 1) / POOL_SPLIT;
    const int s0 = start + split * chunk;
    const int s1 = min(s0 + chunk, end);
    float acc = 0.f;
    for (int n = s0; n < s1; ++n) acc += out[(size_t)n * HC + c];
    if (s0 < s1) atomicAdd(&sums[g * HC + c], acc);
}

// ---- classifier ----
__global__ void classifier_kernel(const float* __restrict__ sums,
                                  const float* __restrict__ cnt,
                                  const float* __restrict__ Wc1,
                                  const float* __restrict__ bc1,
                                  const float* __restrict__ Wc2,
                                  const float* __restrict__ bc2,
                                  float* __restrict__ outp) {
    int g = threadIdx.x;
    if (g >= NUM_GRAPHS) return;
    float inv = 1.0f / cnt[g];
    float hidden[C_CH];
#pragma unroll 4
    for (int j = 0; j < C_CH; ++j) {
        float acc = bc1[j];
        for (int c = 0; c < HC; ++c)
            acc += (sums[g * HC + c] * inv) * Wc1[c * C_CH + j];
        hidden[j] = acc;
    }
    for (int k = 0; k < NUM_CLASSES; ++k) {
        float acc = bc2[k];
#pragma unroll
        for (int j = 0; j < C_CH; ++j) acc += hidden[j] * Wc2[j * NUM_CLASSES + k];
        outp[g * NUM_CLASSES + k] = 1.0f / (1.0f + __expf(-acc));
    }
}

extern "C" void kernel_launch(void* const* d_in, const int* in_sizes, int n_in,
                              void* d_out, int out_size, void* d_ws, size_t ws_size,
                              hipStream_t stream) {
    const float* x   = (const float*)d_in[0];
    const int*   ei  = (const int*)  d_in[1];
    const int*   bat = (const int*)  d_in[2];
    const float* W1  = (const float*)d_in[3];
    const float* as1 = (const float*)d_in[4];
    const float* ad1 = (const float*)d_in[5];
    const float* b1  = (const float*)d_in[6];
    const float* W2  = (const float*)d_in[7];
    const float* as2 = (const float*)d_in[8];
    const float* ad2 = (const float*)d_in[9];
    const float* b2  = (const float*)d_in[10];
    const float* Wc1 = (const float*)d_in[11];
    const float* bc1 = (const float*)d_in[12];
    const float* Wc2 = (const float*)d_in[13];
    const float* bc2 = (const float*)d_in[14];
    float* outp = (float*)d_out;

    char* ws = (char*)d_ws;
    float* obuf = (float*)ws;  ws += (size_t)N_NODES * HC * 4;
    unsigned short* hb16 = (unsigned short*)ws; ws += (size_t)N_NODES * HC * 2;
    float* asb  = (float*)ws;  ws += (size_t)N_NODES * H_HEADS * 4;
    float* adb  = (float*)ws;  ws += (size_t)N_NODES * H_HEADS * 4;
    int* elist    = (int*)ws;  ws += (size_t)ETOT * 4;
    unsigned* bucket_buf = (unsigned*)ws; ws += (size_t)ETOT * 4;
    int* row_start= (int*)ws;  ws += (size_t)N_NODES * 4;
    int* degb     = (int*)ws;  ws += (size_t)N_NODES * 4;
    int* bcursor  = (int*)ws;  ws += (size_t)NBUCK * 4;
    int* bsum     = (int*)ws;  ws += 256 * 4;
    int* gstart   = (int*)ws;  ws += (NUM_GRAPHS + 1) * 4;
    float* sums = (float*)ws;  ws += (size_t)NUM_GRAPHS * HC * 4;
    float* cnt  = (float*)ws;  ws += (size_t)NUM_GRAPHS * 4;

    const int n_blocks   = (N_NODES + 255) / 256;
    const int e_blocks   = (ETOT + 255) / 256;
    const int gemm_blocks = (N_NODES + 63) / 64;
    const int gat_blocks  = (N_NODES + 3) / 4;

    // ---------------- CSR build (shared by both layers) ----------------
    hipMemsetAsync(degb, 0, (size_t)N_NODES * 4, stream);
    count_deg_kernel<<<e_blocks, 256, 0, stream>>>(ei, degb);
    scan_block_kernel<<<SCAN_BLOCKS, 256, 0, stream>>>(degb, row_start, bsum);
    scan_tops_kernel<<<1, 256, 0, stream>>>(bsum);
    scan_add_kernel<<<n_blocks, 256, 0, stream>>>(row_start, bsum, bcursor);
    bucket_scatter_kernel<<<SCAT_BLOCKS, 256, 0, stream>>>(ei, bcursor, bucket_buf);
    bucket_sort_kernel<<<NBUCK, 256, 0, stream>>>(bucket_buf, row_start, elist);

    // ---------------- layer 1 ----------------
    gemm_rb<F_IN_DIM><<<gemm_blocks, 256, 0, stream>>>(x, W1, as1, ad1, hb16, asb, adb);
    gat_gather_kernel<<<gat_blocks, 256, 0, stream>>>(row_start, degb, elist,
                                                      asb, adb, hb16, b1, obuf);

    // ---------------- layer 2 ----------------
    gemm_rb<HC><<<gemm_blocks, 256, 0, stream>>>(obuf, W2, as2, ad2, hb16, asb, adb);
    gat_gather_kernel<<<gat_blocks, 256, 0, stream>>>(row_start, degb, elist,
                                                      asb, adb, hb16, b2, obuf);

    // ---------------- pool + classifier ----------------
    boundary_kernel<<<1, 128, 0, stream>>>(bat, gstart, cnt);
    hipMemsetAsync(sums, 0, (size_t)NUM_GRAPHS * HC * 4, stream);
    pool_seg_kernel<<<NUM_GRAPHS * POOL_SPLIT, 128, 0, stream>>>(obuf, gstart, sums);
    classifier_kernel<<<1, 64, 0, stream>>>(sums, cnt, Wc1, bc1, Wc2, bc2, outp);
}

// Round 14
// 608.847 us; speedup vs baseline: 1.1388x; 1.1388x over previous
//
#include <hip/hip_runtime.h>
#include <math.h>

#define N_NODES 50000
#define E_EDGES 1600000
#define F_IN_DIM 256
#define H_HEADS 4
#define C_CH 32
#define HC 128
#define NUM_CLASSES 16
#define NUM_GRAPHS 64
#define ETOT (E_EDGES + N_NODES)
#define NEG_SLOPE 0.2f
#define SCAN_BLOCKS ((N_NODES + 255) / 256)   // 196
#define NBUCK ((N_NODES + 255) / 256)         // 196 coarse buckets (256 nodes each)
#define SCAT_BLOCKS 512
#define POOL_SPLIT 8

// float -> bf16 (round-to-nearest-even)
__device__ __forceinline__ unsigned short f2bf(float f) {
    unsigned u = __float_as_uint(f);
    return (unsigned short)((u + 0x7FFFu + ((u >> 16) & 1u)) >> 16);
}

// ---- register-blocked GEMM + fused alpha + bf16 output ----
// H16[n,0:128] = bf16(X[n,0:K] @ W[K,128]); as/ad[n,h] = sum_c h*att (fp32, from regs)
template <int K>
__global__ __launch_bounds__(256) void gemm_rb(const float* __restrict__ X,
                                               const float* __restrict__ W,
                                               const float* __restrict__ att_src,
                                               const float* __restrict__ att_dst,
                                               unsigned short* __restrict__ H16,
                                               float* __restrict__ as,
                                               float* __restrict__ ad) {
    __shared__ float xs[32][68];
    const int n0 = blockIdx.x * 64;
    const int tid = threadIdx.x;
    const int rg = tid >> 5;
    const int cg = tid & 31;
    const int r0 = rg * 8;
    const int c0 = cg * 4;
    float acc[8][4];
#pragma unroll
    for (int i = 0; i < 8; ++i)
#pragma unroll
        for (int j = 0; j < 4; ++j) acc[i][j] = 0.f;

    for (int k0 = 0; k0 < K; k0 += 32) {
        __syncthreads();
#pragma unroll
        for (int L = tid; L < 512; L += 256) {
            int row = L >> 3;
            int kq = L & 7;
            int n = n0 + row;
            float4 v = make_float4(0.f, 0.f, 0.f, 0.f);
            if (n < N_NODES)
                v = *reinterpret_cast<const float4*>(&X[(size_t)n * K + k0 + kq * 4]);
            xs[kq * 4 + 0][row] = v.x;
            xs[kq * 4 + 1][row] = v.y;
            xs[kq * 4 + 2][row] = v.z;
            xs[kq * 4 + 3][row] = v.w;
        }
        __syncthreads();
#pragma unroll 8
        for (int k = 0; k < 32; ++k) {
            const float4 w = *reinterpret_cast<const float4*>(&W[(size_t)(k0 + k) * HC + c0]);
            const float4 xa = *reinterpret_cast<const float4*>(&xs[k][r0]);
            const float4 xb = *reinterpret_cast<const float4*>(&xs[k][r0 + 4]);
            acc[0][0] = fmaf(xa.x, w.x, acc[0][0]);
            acc[0][1] = fmaf(xa.x, w.y, acc[0][1]);
            acc[0][2] = fmaf(xa.x, w.z, acc[0][2]);
            acc[0][3] = fmaf(xa.x, w.w, acc[0][3]);
            acc[1][0] = fmaf(xa.y, w.x, acc[1][0]);
            acc[1][1] = fmaf(xa.y, w.y, acc[1][1]);
            acc[1][2] = fmaf(xa.y, w.z, acc[1][2]);
            acc[1][3] = fmaf(xa.y, w.w, acc[1][3]);
            acc[2][0] = fmaf(xa.z, w.x, acc[2][0]);
            acc[2][1] = fmaf(xa.z, w.y, acc[2][1]);
            acc[2][2] = fmaf(xa.z, w.z, acc[2][2]);
            acc[2][3] = fmaf(xa.z, w.w, acc[2][3]);
            acc[3][0] = fmaf(xa.w, w.x, acc[3][0]);
            acc[3][1] = fmaf(xa.w, w.y, acc[3][1]);
            acc[3][2] = fmaf(xa.w, w.z, acc[3][2]);
            acc[3][3] = fmaf(xa.w, w.w, acc[3][3]);
            acc[4][0] = fmaf(xb.x, w.x, acc[4][0]);
            acc[4][1] = fmaf(xb.x, w.y, acc[4][1]);
            acc[4][2] = fmaf(xb.x, w.z, acc[4][2]);
            acc[4][3] = fmaf(xb.x, w.w, acc[4][3]);
            acc[5][0] = fmaf(xb.y, w.x, acc[5][0]);
            acc[5][1] = fmaf(xb.y, w.y, acc[5][1]);
            acc[5][2] = fmaf(xb.y, w.z, acc[5][2]);
            acc[5][3] = fmaf(xb.y, w.w, acc[5][3]);
            acc[6][0] = fmaf(xb.z, w.x, acc[6][0]);
            acc[6][1] = fmaf(xb.z, w.y, acc[6][1]);
            acc[6][2] = fmaf(xb.z, w.z, acc[6][2]);
            acc[6][3] = fmaf(xb.z, w.w, acc[6][3]);
            acc[7][0] = fmaf(xb.w, w.x, acc[7][0]);
            acc[7][1] = fmaf(xb.w, w.y, acc[7][1]);
            acc[7][2] = fmaf(xb.w, w.z, acc[7][2]);
            acc[7][3] = fmaf(xb.w, w.w, acc[7][3]);
        }
    }
    // epilogue: bf16 store + fused alpha (head h = cg>>3, channels c0..c0+3)
    const int h = cg >> 3;
    const int cb = c0 & 31;
    const float4 av = *reinterpret_cast<const float4*>(&att_src[h * C_CH + cb]);
    const float4 dv = *reinterpret_cast<const float4*>(&att_dst[h * C_CH + cb]);
#pragma unroll
    for (int i = 0; i < 8; ++i) {
        int n = n0 + r0 + i;
        float sa = acc[i][0] * av.x + acc[i][1] * av.y + acc[i][2] * av.z + acc[i][3] * av.w;
        float sd = acc[i][0] * dv.x + acc[i][1] * dv.y + acc[i][2] * dv.z + acc[i][3] * dv.w;
#pragma unroll
        for (int off = 1; off < 8; off <<= 1) {
            sa += __shfl_xor(sa, off, 64);
            sd += __shfl_xor(sd, off, 64);
        }
        if (n < N_NODES) {
            ushort4 b;
            b.x = f2bf(acc[i][0]);
            b.y = f2bf(acc[i][1]);
            b.z = f2bf(acc[i][2]);
            b.w = f2bf(acc[i][3]);
            *reinterpret_cast<ushort4*>(&H16[(size_t)n * HC + c0]) = b;
            if ((cg & 7) == 0) {
                as[n * 4 + h] = sa;
                ad[n * 4 + h] = sd;
            }
        }
    }
}

// ================= CSR build (once per call) =================
__global__ void count_deg_kernel(const int* __restrict__ ei, int* __restrict__ deg) {
    int e = blockIdx.x * blockDim.x + threadIdx.x;
    if (e >= ETOT) return;
    int d = (e < E_EDGES) ? ei[E_EDGES + e] : (e - E_EDGES);
    atomicAdd(&deg[d], 1);
}

__global__ __launch_bounds__(256) void scan_block_kernel(const int* __restrict__ deg,
                                                         int* __restrict__ excl,
                                                         int* __restrict__ bsum) {
    __shared__ int tmp[256];
    int i = blockIdx.x * 256 + threadIdx.x;
    int v = (i < N_NODES) ? deg[i] : 0;
    tmp[threadIdx.x] = v;
    __syncthreads();
    for (int off = 1; off < 256; off <<= 1) {
        int t = (threadIdx.x >= off) ? tmp[threadIdx.x - off] : 0;
        __syncthreads();
        tmp[threadIdx.x] += t;
        __syncthreads();
    }
    if (i < N_NODES) excl[i] = tmp[threadIdx.x] - v;
    if (threadIdx.x == 255) bsum[blockIdx.x] = tmp[255];
}

__global__ __launch_bounds__(256) void scan_tops_kernel(int* __restrict__ bsum) {
    __shared__ int tmp[256];
    int t = threadIdx.x;
    int v = (t < SCAN_BLOCKS) ? bsum[t] : 0;
    tmp[t] = v;
    __syncthreads();
    for (int off = 1; off < 256; off <<= 1) {
        int u = (t >= off) ? tmp[t - off] : 0;
        __syncthreads();
        tmp[t] += u;
        __syncthreads();
    }
    if (t < SCAN_BLOCKS) bsum[t] = tmp[t] - v;
}

// finalize row_start; seed per-bucket cursors for the coarse scatter
__global__ void scan_add_kernel(int* __restrict__ excl, const int* __restrict__ bsum,
                                int* __restrict__ bcursor) {
    int i = blockIdx.x * blockDim.x + threadIdx.x;
    if (i >= N_NODES) return;
    int s = excl[i] + bsum[i >> 8];
    excl[i] = s;                              // row_start
    if ((i & 255) == 0) bcursor[i >> 8] = s;  // bucket base
}

// ---- coarse scatter: bin packed edges (d<<16|s) by d>>8 ----
__global__ __launch_bounds__(256) void bucket_scatter_kernel(const int* __restrict__ ei,
                                                             int* __restrict__ bcursor,
                                                             unsigned* __restrict__ bucket_buf) {
    __shared__ int hist[NBUCK];
    __shared__ int base[NBUCK];
    const int tid = threadIdx.x;
    const int chunk = (ETOT + SCAT_BLOCKS - 1) / SCAT_BLOCKS;
    const int e0 = blockIdx.x * chunk;
    const int e1 = min(e0 + chunk, ETOT);
    for (int i = tid; i < NBUCK; i += 256) hist[i] = 0;
    __syncthreads();
    for (int e = e0 + tid; e < e1; e += 256) {
        int d = (e < E_EDGES) ? ei[E_EDGES + e] : (e - E_EDGES);
        atomicAdd(&hist[d >> 8], 1);
    }
    __syncthreads();
    for (int i = tid; i < NBUCK; i += 256) {
        int cnt = hist[i];
        base[i] = (cnt > 0) ? atomicAdd(&bcursor[i], cnt) : 0;
        hist[i] = 0;  // reuse as local cursor
    }
    __syncthreads();
    for (int e = e0 + tid; e < e1; e += 256) {
        int s, d;
        if (e < E_EDGES) { s = ei[e]; d = ei[E_EDGES + e]; }
        else             { s = d = e - E_EDGES; }
        int b = d >> 8;
        int pos = base[b] + atomicAdd(&hist[b], 1);
        bucket_buf[pos] = ((unsigned)d << 16) | (unsigned)s;
    }
}

// ---- fine scatter: one block per bucket, LDS cursors, private window ----
__global__ __launch_bounds__(256) void bucket_sort_kernel(const unsigned* __restrict__ bucket_buf,
                                                          const int* __restrict__ row_start,
                                                          int* __restrict__ elist) {
    __shared__ int cur[256];
    const int b = blockIdx.x;
    const int n0 = b * 256;
    const int tid = threadIdx.x;
    if (n0 + tid < N_NODES) cur[tid] = row_start[n0 + tid];
    const int start = row_start[n0];
    const int end = (b == NBUCK - 1) ? ETOT : row_start[n0 + 256];
    __syncthreads();
    for (int j = start + tid; j < end; j += 256) {
        unsigned p = bucket_buf[j];
        int d = (int)(p >> 16);
        int s = (int)(p & 0xffffu);
        int pos = atomicAdd(&cur[d - n0], 1);
        elist[pos] = s;
    }
}

// ============ fused gather GAT: chunked flash softmax + bf16 gather ============
// (round-11 structure, measured 87.7 us: LDS-broadcast sbuf/pbuf keeps gather
// addresses independent -> MLP; dependent-shfl variant regressed to 120 us)
__global__ __launch_bounds__(128) void gat_gather_kernel(const int* __restrict__ row_start,
                                                         const int* __restrict__ deg,
                                                         const int* __restrict__ elist,
                                                         const float* __restrict__ as,
                                                         const float* __restrict__ ad,
                                                         const unsigned short* __restrict__ H16,
                                                         const float* __restrict__ bias,
                                                         float* __restrict__ out) {
    const int n = blockIdx.x;
    const int t = threadIdx.x;
    const int c = t;            // channel (gather phase)
    const int hg = t >> 5;      // head
    const int j32 = t & 31;     // edge-in-chunk (softmax phase)
    const int row = row_start[n];
    const int len = deg[n];
    const float ad_n = ad[n * 4 + hg];

    __shared__ int   sbuf[32];
    __shared__ float pbuf[4][32];

    float m = -INFINITY, z = 0.f, acc = 0.f;

    for (int base = 0; base < len; base += 32) {
        const int cl = min(32, len - base);
        if (t < cl) sbuf[t] = elist[row + base + t];
        __syncthreads();

        float ev = -INFINITY;
        if (j32 < cl) {
            int s = sbuf[j32];
            ev = as[s * 4 + hg] + ad_n;
            ev = ev > 0.f ? ev : ev * NEG_SLOPE;
        }
        float cm = ev;
#pragma unroll
        for (int off = 16; off > 0; off >>= 1)
            cm = fmaxf(cm, __shfl_xor(cm, off, 32));
        float mnew = fmaxf(m, cm);
        float scale = __expf(m - mnew);
        z *= scale;
        acc *= scale;
        m = mnew;
        float p = (j32 < cl) ? __expf(ev - m) : 0.f;
        float ps = p;
#pragma unroll
        for (int off = 16; off > 0; off >>= 1)
            ps += __shfl_xor(ps, off, 32);
        z += ps;
        pbuf[hg][j32] = p;
        __syncthreads();

        for (int j = 0; j < cl; ++j) {
            int s = sbuf[j];
            unsigned short us = H16[(size_t)s * HC + c];
            float hv = __uint_as_float((unsigned)us << 16);
            acc = fmaf(pbuf[hg][j], hv, acc);
        }
        __syncthreads();
    }
    float v = acc / z + bias[c];
    out[(size_t)n * HC + c] = v > 0.f ? v : 0.f;
}

// ---- graph boundaries via binary search on sorted batch ----
__global__ void boundary_kernel(const int* __restrict__ batch,
                                int* __restrict__ gstart,
                                float* __restrict__ cntf) {
    int g = threadIdx.x;
    if (g <= NUM_GRAPHS) {
        int lo = 0, hi = N_NODES;
        while (lo < hi) {
            int mid = (lo + hi) >> 1;
            if (batch[mid] < g) lo = mid + 1; else hi = mid;
        }
        gstart[g] = lo;
    }
    __syncthreads();
    if (g < NUM_GRAPHS) cntf[g] = (float)(gstart[g + 1] - gstart[g]);
}

// ---- pool: 8 blocks per graph, register accumulation, 1 atomic per thread ----
__global__ __launch_bounds__(128) void pool_seg_kernel(const float* __restrict__ out,
                                                       const int* __restrict__ gstart,
                                                       float* __restrict__ sums) {
    const int g = blockIdx.x >> 3;
    const int split = blockIdx.x & 7;
    const int c = threadIdx.x;
    const int start = gstart[g], end = gstart[g + 1];
    const int len = end - start;
    const int chunk = (len + POOL_SPLIT - 1) / POOL_SPLIT;
    const int s0 = start + split * chunk;
    const int s1 = min(s0 + chunk, end);
    float acc = 0.f;
    for (int n = s0; n < s1; ++n) acc += out[(size_t)n * HC + c];
    if (s0 < s1) atomicAdd(&sums[g * HC + c], acc);
}

// ---- classifier ----
__global__ void classifier_kernel(const float* __restrict__ sums,
                                  const float* __restrict__ cnt,
                                  const float* __restrict__ Wc1,
                                  const float* __restrict__ bc1,
                                  const float* __restrict__ Wc2,
                                  const float* __restrict__ bc2,
                                  float* __restrict__ outp) {
    int g = threadIdx.x;
    if (g >= NUM_GRAPHS) return;
    float inv = 1.0f / cnt[g];
    float hidden[C_CH];
#pragma unroll 4
    for (int j = 0; j < C_CH; ++j) {
        float acc = bc1[j];
        for (int c = 0; c < HC; ++c)
            acc += (sums[g * HC + c] * inv) * Wc1[c * C_CH + j];
        hidden[j] = acc;
    }
    for (int k = 0; k < NUM_CLASSES; ++k) {
        float acc = bc2[k];
#pragma unroll
        for (int j = 0; j < C_CH; ++j) acc += hidden[j] * Wc2[j * NUM_CLASSES + k];
        outp[g * NUM_CLASSES + k] = 1.0f / (1.0f + __expf(-acc));
    }
}

extern "C" void kernel_launch(void* const* d_in, const int* in_sizes, int n_in,
                              void* d_out, int out_size, void* d_ws, size_t ws_size,
                              hipStream_t stream) {
    const float* x   = (const float*)d_in[0];
    const int*   ei  = (const int*)  d_in[1];
    const int*   bat = (const int*)  d_in[2];
    const float* W1  = (const float*)d_in[3];
    const float* as1 = (const float*)d_in[4];
    const float* ad1 = (const float*)d_in[5];
    const float* b1  = (const float*)d_in[6];
    const float* W2  = (const float*)d_in[7];
    const float* as2 = (const float*)d_in[8];
    const float* ad2 = (const float*)d_in[9];
    const float* b2  = (const float*)d_in[10];
    const float* Wc1 = (const float*)d_in[11];
    const float* bc1 = (const float*)d_in[12];
    const float* Wc2 = (const float*)d_in[13];
    const float* bc2 = (const float*)d_in[14];
    float* outp = (float*)d_out;

    char* ws = (char*)d_ws;
    float* obuf = (float*)ws;  ws += (size_t)N_NODES * HC * 4;
    unsigned short* hb16 = (unsigned short*)ws; ws += (size_t)N_NODES * HC * 2;
    float* asb  = (float*)ws;  ws += (size_t)N_NODES * H_HEADS * 4;
    float* adb  = (float*)ws;  ws += (size_t)N_NODES * H_HEADS * 4;
    int* elist    = (int*)ws;  ws += (size_t)ETOT * 4;
    unsigned* bucket_buf = (unsigned*)ws; ws += (size_t)ETOT * 4;
    int* row_start= (int*)ws;  ws += (size_t)N_NODES * 4;
    int* degb     = (int*)ws;  ws += (size_t)N_NODES * 4;
    int* bcursor  = (int*)ws;  ws += (size_t)NBUCK * 4;
    int* bsum     = (int*)ws;  ws += 256 * 4;
    int* gstart   = (int*)ws;  ws += (NUM_GRAPHS + 1) * 4;
    float* sums = (float*)ws;  ws += (size_t)NUM_GRAPHS * HC * 4;
    float* cnt  = (float*)ws;  ws += (size_t)NUM_GRAPHS * 4;

    const int n_blocks   = (N_NODES + 255) / 256;
    const int e_blocks   = (ETOT + 255) / 256;
    const int gemm_blocks = (N_NODES + 63) / 64;

    // ---------------- CSR build (shared by both layers) ----------------
    hipMemsetAsync(degb, 0, (size_t)N_NODES * 4, stream);
    count_deg_kernel<<<e_blocks, 256, 0, stream>>>(ei, degb);
    scan_block_kernel<<<SCAN_BLOCKS, 256, 0, stream>>>(degb, row_start, bsum);
    scan_tops_kernel<<<1, 256, 0, stream>>>(bsum);
    scan_add_kernel<<<n_blocks, 256, 0, stream>>>(row_start, bsum, bcursor);
    bucket_scatter_kernel<<<SCAT_BLOCKS, 256, 0, stream>>>(ei, bcursor, bucket_buf);
    bucket_sort_kernel<<<NBUCK, 256, 0, stream>>>(bucket_buf, row_start, elist);

    // ---------------- layer 1 ----------------
    gemm_rb<F_IN_DIM><<<gemm_blocks, 256, 0, stream>>>(x, W1, as1, ad1, hb16, asb, adb);
    gat_gather_kernel<<<N_NODES, 128, 0, stream>>>(row_start, degb, elist,
                                                   asb, adb, hb16, b1, obuf);

    // ---------------- layer 2 ----------------
    gemm_rb<HC><<<gemm_blocks, 256, 0, stream>>>(obuf, W2, as2, ad2, hb16, asb, adb);
    gat_gather_kernel<<<N_NODES, 128, 0, stream>>>(row_start, degb, elist,
                                                   asb, adb, hb16, b2, obuf);

    // ---------------- pool + classifier ----------------
    boundary_kernel<<<1, 128, 0, stream>>>(bat, gstart, cnt);
    hipMemsetAsync(sums, 0, (size_t)NUM_GRAPHS * HC * 4, stream);
    pool_seg_kernel<<<NUM_GRAPHS * POOL_SPLIT, 128, 0, stream>>>(obuf, gstart, sums);
    classifier_kernel<<<1, 64, 0, stream>>>(sums, cnt, Wc1, bc1, Wc2, bc2, outp);
}